// Round 2
// baseline (267.528 us; speedup 1.0000x reference)
//
#include <hip/hip_runtime.h>

#define NJ   21
#define HID  10
#define FT   6

// One thread per batch element. Fully unrolled kinematic chain: all weight
// indices are compile-time constants -> uniform (scalar) loads on the SMEM
// pipe; VALU does ~3300 v_fmac_f32 with SGPR weight operands.
__global__ __launch_bounds__(256) void se_kernel(
    const float* __restrict__ quat,   // [B, 21, 4]
    const float* __restrict__ W1r,    // [10, 4]
    const float* __restrict__ b1r,    // [10]
    const float* __restrict__ W1,     // [20, 10, 10]
    const float* __restrict__ b1,     // [20, 10]
    const float* __restrict__ W2,     // [21, 6, 10]
    const float* __restrict__ b2,     // [21, 6]
    float*       __restrict__ out,    // [B, 126]
    int B)
{
    constexpr int kPar[NJ] = {-1,0,0,0,1,2,3,4,5,6,7,8,9,9,9,12,13,14,16,17,18};

    const int b = blockIdx.x * blockDim.x + threadIdx.x;
    if (b >= B) return;

    // quat + b*84 floats: byte offset b*336, 16B-aligned -> float4 loads OK.
    const float4* __restrict__ qv = reinterpret_cast<const float4*>(quat) + (size_t)b * NJ;
    float* __restrict__ op = out + (size_t)b * (NJ * FT);   // byte offset b*504: 8B-aligned

    float feat[NJ][FT];   // constant indices -> registers; liveness per joint is short

    // ---- joint 0 (root): in = quat[b,0,0:4] ----
    {
        const float4 q0 = qv[0];
        float h[HID];
        #pragma unroll
        for (int r = 0; r < HID; ++r) {
            float acc = b1r[r];
            acc = fmaf(W1r[r*4+0], q0.x, acc);
            acc = fmaf(W1r[r*4+1], q0.y, acc);
            acc = fmaf(W1r[r*4+2], q0.z, acc);
            acc = fmaf(W1r[r*4+3], q0.w, acc);
            h[r] = fmaxf(acc, 0.0f);
        }
        #pragma unroll
        for (int r = 0; r < FT; ++r) {
            float acc = b2[r];
            #pragma unroll
            for (int c = 0; c < HID; ++c)
                acc = fmaf(W2[r*HID + c], h[c], acc);
            feat[0][r] = fmaxf(acc, 0.0f);
        }
        float2* o2 = reinterpret_cast<float2*>(op);          // 8B-aligned
        #pragma unroll
        for (int r = 0; r < FT/2; ++r)
            o2[r] = make_float2(feat[0][2*r], feat[0][2*r+1]);
    }

    // ---- joints 1..20: in = concat(quat[b,i,:], feat[parent]) ----
    #pragma unroll
    for (int i = 1; i < NJ; ++i) {
        const int p = kPar[i];
        const float4 qi = qv[i];
        float inp[HID] = { qi.x, qi.y, qi.z, qi.w,
                           feat[p][0], feat[p][1], feat[p][2],
                           feat[p][3], feat[p][4], feat[p][5] };
        float hh[HID];
        #pragma unroll
        for (int r = 0; r < HID; ++r) {
            float acc = b1[(i-1)*HID + r];
            #pragma unroll
            for (int c = 0; c < HID; ++c)
                acc = fmaf(W1[((i-1)*HID + r)*HID + c], inp[c], acc);
            hh[r] = fmaxf(acc, 0.0f);
        }
        #pragma unroll
        for (int r = 0; r < FT; ++r) {
            float acc = b2[i*FT + r];
            #pragma unroll
            for (int c = 0; c < HID; ++c)
                acc = fmaf(W2[(i*FT + r)*HID + c], hh[c], acc);
            feat[i][r] = fmaxf(acc, 0.0f);
        }
        float2* o2 = reinterpret_cast<float2*>(op + i*FT);   // b*504 + i*24: 8B-aligned
        #pragma unroll
        for (int r = 0; r < FT/2; ++r)
            o2[r] = make_float2(feat[i][2*r], feat[i][2*r+1]);
    }
}

extern "C" void kernel_launch(void* const* d_in, const int* in_sizes, int n_in,
                              void* d_out, int out_size, void* d_ws, size_t ws_size,
                              hipStream_t stream) {
    const float* quat = (const float*)d_in[0];
    const float* W1r  = (const float*)d_in[1];
    const float* b1r  = (const float*)d_in[2];
    const float* W1   = (const float*)d_in[3];
    const float* b1   = (const float*)d_in[4];
    const float* W2   = (const float*)d_in[5];
    const float* b2   = (const float*)d_in[6];
    float* out = (float*)d_out;

    const int B = in_sizes[0] / (NJ * 4);
    const int threads = 256;
    const int blocks  = (B + threads - 1) / threads;
    se_kernel<<<blocks, threads, 0, stream>>>(quat, W1r, b1r, W1, b1, W2, b2, out, B);
}

// Round 3
// 256.385 us; speedup vs baseline: 1.0435x; 1.0435x over previous
//
#include <hip/hip_runtime.h>

#define NJ  21
#define HID 10
#define FT  6

// One thread per batch element. NO large local arrays (rule: runtime-indexed
// or >threshold allocas go to scratch -> 21 serial vmcnt round-trips, the
// round-2 pathology: VGPR=24, +246MB spill writes, +73MB reloads, 267us).
// Instead: per-joint 6-float locals declared in DFS tree order (<=3 live),
// constant-index only, output stored immediately (direct float2 stores merged
// to ideal 264MB in L2 per round-2 counters).

__device__ __forceinline__ void joint_mlp(const float inp[HID],
                                          const float* __restrict__ W1j,
                                          const float* __restrict__ b1j,
                                          const float* __restrict__ W2j,
                                          const float* __restrict__ b2j,
                                          float f[FT])
{
    float h[HID];
    #pragma unroll
    for (int r = 0; r < HID; ++r) {
        float acc = b1j[r];
        #pragma unroll
        for (int c = 0; c < HID; ++c)
            acc = fmaf(W1j[r*HID + c], inp[c], acc);
        h[r] = fmaxf(acc, 0.0f);
    }
    #pragma unroll
    for (int r = 0; r < FT; ++r) {
        float acc = b2j[r];
        #pragma unroll
        for (int c = 0; c < HID; ++c)
            acc = fmaf(W2j[r*HID + c], h[c], acc);
        f[r] = fmaxf(acc, 0.0f);
    }
}

__global__ __launch_bounds__(256, 4) void se_kernel(
    const float* __restrict__ quat,   // [B, 21, 4]
    const float* __restrict__ W1r,    // [10, 4]
    const float* __restrict__ b1r,    // [10]
    const float* __restrict__ W1,     // [20, 10, 10]
    const float* __restrict__ b1,     // [20, 10]
    const float* __restrict__ W2,     // [21, 6, 10]
    const float* __restrict__ b2,     // [21, 6]
    float*       __restrict__ out,    // [B, 126]
    int B)
{
    const int b = blockIdx.x * blockDim.x + threadIdx.x;
    if (b >= B) return;

    const float4* __restrict__ qv = reinterpret_cast<const float4*>(quat) + (size_t)b * NJ;
    float* __restrict__ op = out + (size_t)b * (NJ * FT);

    // store immediately; wave store footprint is contiguous 32KB -> L2 merges
#define STORE_F(j, f) { \
        float2* o2 = reinterpret_cast<float2*>(op + (j)*FT); \
        o2[0] = make_float2(f[0], f[1]); \
        o2[1] = make_float2(f[2], f[3]); \
        o2[2] = make_float2(f[4], f[5]); }

#define DO_JOINT(j, fpar, fout) { \
        const float4 q = qv[j]; \
        const float inp[HID] = { q.x, q.y, q.z, q.w, \
            fpar[0], fpar[1], fpar[2], fpar[3], fpar[4], fpar[5] }; \
        joint_mlp(inp, W1 + ((j)-1)*HID*HID, b1 + ((j)-1)*HID, \
                  W2 + (j)*FT*HID, b2 + (j)*FT, fout); \
        STORE_F(j, fout); }

    // ---- root (joint 0): in = quat only ----
    float f0[FT];
    {
        const float4 q0 = qv[0];
        float h[HID];
        #pragma unroll
        for (int r = 0; r < HID; ++r) {
            float acc = b1r[r];
            acc = fmaf(W1r[r*4+0], q0.x, acc);
            acc = fmaf(W1r[r*4+1], q0.y, acc);
            acc = fmaf(W1r[r*4+2], q0.z, acc);
            acc = fmaf(W1r[r*4+3], q0.w, acc);
            h[r] = fmaxf(acc, 0.0f);
        }
        #pragma unroll
        for (int r = 0; r < FT; ++r) {
            float acc = b2[r];
            #pragma unroll
            for (int c = 0; c < HID; ++c)
                acc = fmaf(W2[r*HID + c], h[c], acc);
            f0[r] = fmaxf(acc, 0.0f);
        }
        STORE_F(0, f0);
    }

    // ---- DFS over the kinematic tree; <=3 feat locals live at once ----
    // chain 0-1-4-7-10
    float f1[FT], f4[FT], f7[FT], f10[FT];
    DO_JOINT(1,  f0,  f1);
    DO_JOINT(4,  f1,  f4);
    DO_JOINT(7,  f4,  f7);
    DO_JOINT(10, f7,  f10);
    // chain 0-2-5-8-11
    float f2[FT], f5[FT], f8[FT], f11[FT];
    DO_JOINT(2,  f0,  f2);
    DO_JOINT(5,  f2,  f5);
    DO_JOINT(8,  f5,  f8);
    DO_JOINT(11, f8,  f11);
    // chain 0-3-6-9
    float f3[FT], f6[FT], f9[FT];
    DO_JOINT(3,  f0,  f3);
    DO_JOINT(6,  f3,  f6);
    DO_JOINT(9,  f6,  f9);
    // 9 -> 12 -> 15
    float f12[FT], f15[FT];
    DO_JOINT(12, f9,  f12);
    DO_JOINT(15, f12, f15);
    // 9 -> 13 -> 16 -> 18 -> 20
    float f13[FT], f16[FT], f18[FT], f20[FT];
    DO_JOINT(13, f9,  f13);
    DO_JOINT(16, f13, f16);
    DO_JOINT(18, f16, f18);
    DO_JOINT(20, f18, f20);
    // 9 -> 14 -> 17 -> 19
    float f14[FT], f17[FT], f19[FT];
    DO_JOINT(14, f9,  f14);
    DO_JOINT(17, f14, f17);
    DO_JOINT(19, f17, f19);

#undef DO_JOINT
#undef STORE_F
}

extern "C" void kernel_launch(void* const* d_in, const int* in_sizes, int n_in,
                              void* d_out, int out_size, void* d_ws, size_t ws_size,
                              hipStream_t stream) {
    const float* quat = (const float*)d_in[0];
    const float* W1r  = (const float*)d_in[1];
    const float* b1r  = (const float*)d_in[2];
    const float* W1   = (const float*)d_in[3];
    const float* b1   = (const float*)d_in[4];
    const float* W2   = (const float*)d_in[5];
    const float* b2   = (const float*)d_in[6];
    float* out = (float*)d_out;

    const int B = in_sizes[0] / (NJ * 4);
    const int threads = 256;
    const int blocks  = (B + threads - 1) / threads;
    se_kernel<<<blocks, threads, 0, stream>>>(quat, W1r, b1r, W1, b1, W2, b2, out, B);
}